// Round 18
// baseline (250.101 us; speedup 1.0000x reference)
//
#include <hip/hip_runtime.h>
#include <hip/hip_bf16.h>

// Problem constants
#define NN 10000
#define EE 160000
#define IN_DIM 128
#define HID 128
#define HEADS 8
#define F1 (HEADS*HID)   // 1024
#define INT_DIM 512
#define OUT_DIM 3
#define MPAD 10112       // 79 * 128

typedef __attribute__((ext_vector_type(4))) float f32x4;
typedef __attribute__((ext_vector_type(8))) _Float16 half8;
typedef __attribute__((ext_vector_type(4))) _Float16 half4;
typedef __attribute__((ext_vector_type(2))) _Float16 half2v;

// wave-local LDS fence: wait all this wave's DS ops, and pin program order
#define WAVE_SYNC() do { asm volatile("s_waitcnt lgkmcnt(0)" ::: "memory"); \
                         __builtin_amdgcn_sched_barrier(0); } while(0)

// fp32 acc += f32(w) * f16-half-of(pair)  — v_fma_mix_f32, no separate cvt
#define FMA_MIX_LO(acc, pair, w) asm("v_fma_mix_f32 %0, %1, %2, %0 op_sel:[0,0,0] op_sel_hi:[1,0,0]" \
                                     : "+v"(acc) : "v"(pair), "v"(w))
#define FMA_MIX_HI(acc, pair, w) asm("v_fma_mix_f32 %0, %1, %2, %0 op_sel:[1,0,0] op_sel_hi:[1,0,0]" \
                                     : "+v"(acc) : "v"(pair), "v"(w))

__device__ inline void fma_mix8(float* acc, uint4 v, float w){
    FMA_MIX_LO(acc[0], v.x, w);  FMA_MIX_HI(acc[1], v.x, w);
    FMA_MIX_LO(acc[2], v.y, w);  FMA_MIX_HI(acc[3], v.y, w);
    FMA_MIX_LO(acc[4], v.z, w);  FMA_MIX_HI(acc[5], v.z, w);
    FMA_MIX_LO(acc[6], v.w, w);  FMA_MIX_HI(acc[7], v.w, w);
}

// ---------------- CSR build ----------------
// single-pass 1024-thread scan: 10 elems/thread serial + shfl wave-scan + cross-wave
__global__ __launch_bounds__(1024) void scan_kernel(const int* __restrict__ cnt, int* __restrict__ rowp,
                                                    int* __restrict__ cursor, int n){
    int t = threadIdx.x;
    int base = t*10;
    int vals[10];
    int run = 0;
    #pragma unroll
    for(int k=0;k<10;k++){
        int i = base+k;
        int v = (i<n) ? cnt[i] : 0;
        vals[k] = run;           // exclusive within thread
        run += v;
    }
    int lane = t & 63, wv = t >> 6;
    int inc = run;               // inclusive wave scan of thread totals
    #pragma unroll
    for(int off=1; off<64; off<<=1){
        int u = __shfl_up(inc, off);
        if(lane >= off) inc += u;
    }
    __shared__ int wtot[16], woff[16];
    if(lane == 63) wtot[wv] = inc;
    __syncthreads();
    if(t < 16){
        int v = wtot[t];
        int inc2 = v;
        #pragma unroll
        for(int off=1; off<16; off<<=1){
            int u = __shfl_up(inc2, off);
            if(t >= off) inc2 += u;
        }
        woff[t] = inc2 - v;      // exclusive wave offset
    }
    __syncthreads();
    int thread_excl = woff[wv] + inc - run;
    #pragma unroll
    for(int k=0;k<10;k++){
        int i = base+k;
        if(i<n){
            int v = thread_excl + vals[k];
            rowp[i] = v;
            cursor[i] = v;
        }
    }
    if(t == 1023) rowp[n] = thread_excl + run;
}

__global__ __launch_bounds__(256) void fill_kernel(const int* __restrict__ src, const int* __restrict__ dst,
                                                   int E, int* __restrict__ cursor, int* __restrict__ colsrc){
    int e = blockIdx.x*256 + threadIdx.x;
    if(e < E){
        int d = dst[e];
        int pos = atomicAdd(&cursor[d], 1);
        colsrc[pos] = src[e];
    }
}

// ---------------- fused prep: 4 weight transposes + x->fp16 + aw1 + cnt zero ----------------
__device__ inline void transpose_tile16(const float* __restrict__ B, _Float16* __restrict__ T,
                                        int K, int N, int idx){
    __shared__ float tile[32][33];
    const int tx = threadIdx.x & 31, ty = threadIdx.x >> 5;   // 32 x 8
    const int gx = N >> 5;
    const int n0 = (idx % gx) * 32, k0 = (idx / gx) * 32;
    #pragma unroll
    for(int i = 0; i < 32; i += 8)
        tile[ty + i][tx] = B[(size_t)(k0 + ty + i) * N + n0 + tx];
    __syncthreads();
    #pragma unroll
    for(int i = 0; i < 32; i += 8){
        int nn = ty + i;
        T[(size_t)(n0 + nn) * K + k0 + tx] = (_Float16)tile[tx][nn];
    }
}

__global__ __launch_bounds__(256) void prep_kernel(
    const float* __restrict__ W1, const float* __restrict__ W2,
    const float* __restrict__ W3, const float* __restrict__ Wl,
    const float* __restrict__ x,
    const float* __restrict__ a_src1, const float* __restrict__ a_dst1,
    _Float16* __restrict__ tW1, _Float16* __restrict__ tW2,
    _Float16* __restrict__ tW3, _Float16* __restrict__ tWl,
    _Float16* __restrict__ x16, float* __restrict__ aw,
    int* __restrict__ cnt)
{
    int b = blockIdx.x;
    if(b < 128){            transpose_tile16(W1, tW1, IN_DIM, F1, b); }
    else if(b < 1152){      transpose_tile16(W2, tW2, F1, F1, b-128); }
    else if(b < 1664){      transpose_tile16(W3, tW3, F1, INT_DIM, b-1152); }
    else if(b < 1920){      transpose_tile16(Wl, tWl, INT_DIM, INT_DIM, b-1664); }
    else if(b < 3170){
        int i = (b-1920)*256 + threadIdx.x;     // < 320000 exactly
        float4 v = ((const float4*)x)[i];
        half4 o = { (_Float16)v.x, (_Float16)v.y, (_Float16)v.z, (_Float16)v.w };
        ((half4*)x16)[i] = o;
    }
    else if(b < 3178){
        int idx = (b-3170)*256 + threadIdx.x;
        if(idx < 16*IN_DIM){
            int j = idx >> 7, k = idx & 127;
            int hj = j & 7;
            const float* av = (j < 8 ? a_src1 : a_dst1) + hj*HID;
            const float* wr = W1 + (size_t)k*F1 + hj*HID;
            float s = 0.f;
            #pragma unroll 4
            for(int c = 0; c < HID; c++) s += av[c] * wr[c];
            aw[idx] = s;
        }
    }
    else {
        int i = (b-3178)*1024 + threadIdx.x*4;
        if(i < NN) *(int4*)(cnt + i) = (int4){0,0,0,0};   // NN%4==0
    }
}

// ---------------- fused: count (blocks 0..624) + alpha1 (blocks 625..1249) ----------------
__global__ __launch_bounds__(256) void count_alpha1_kernel(
    const int* __restrict__ dst, int* __restrict__ cnt,
    const float* __restrict__ x, const float* __restrict__ aw,
    float* __restrict__ asrc, float* __restrict__ adst)
{
    int b = blockIdx.x;
    if(b < 625){
        int e = b*256 + threadIdx.x;
        if(e < EE) atomicAdd(&cnt[dst[e]], 1);
        return;
    }
    __shared__ float xs[16][128];
    __shared__ float aws[16][128];
    int t = threadIdx.x;
    int nb = (b - 625) * 16;
    for(int i = t; i < 16*128; i += 256){
        xs[i >> 7][i & 127] = x[(size_t)nb*128 + i];
        aws[i >> 7][i & 127] = aw[i];
    }
    __syncthreads();
    int nl = t >> 4, j = t & 15;
    float s = 0.f;
    #pragma unroll 4
    for(int c = 0; c < 128; c++) s += xs[nl][c] * aws[j][c];
    int node = nb + nl;
    if(j < 8) asrc[node*8 + j] = s;
    else      adst[node*8 + (j-8)] = s;
}

// ---------------- agg1: per-head softmax-agg of fp16 x; 4 nodes/block, 1 wave/node; emits fp16 ----------------
__global__ __launch_bounds__(256) void agg1_kernel(const _Float16* __restrict__ x16,
                                                   const float* __restrict__ asrc,
                                                   const float* __restrict__ adst,
                                                   const int* __restrict__ rowp,
                                                   const int* __restrict__ colsrc,
                                                   _Float16* __restrict__ oa){
    const int w = threadIdx.x >> 6, l = threadIdx.x & 63;
    const int node = blockIdx.x*4 + w;
    __shared__ float sh_ee[4][64][8];
    int beg = rowp[node], end = rowp[node+1];
    float rd = adst[node*8 + (l & 7)];
    float acc0[8], acc1[8];
    #pragma unroll
    for(int h=0;h<8;h++){ acc0[h]=0.f; acc1[h]=0.f; }
    float dpart = 0.f;
    const char* xb = (const char*)x16 + 4*l;
    for(int base=beg; base<end; base+=64){
        int clen = min(64, end-base);
        WAVE_SYNC();                        // prior chunk's ee reads complete
        unsigned soff = 0;
        if(l < clen) soff = (unsigned)colsrc[base + l] << 8;   // row byte offset (256B rows)
        for(int it=l; it<clen*8; it+=64){
            int j = it >> 3;
            int s = colsrc[base + j];
            float e = asrc[s*8 + (l & 7)] + rd;
            e = (e > 0.f) ? e : 0.2f*e;
            float ee = expf(e);
            sh_ee[w][j][l & 7] = ee;
            dpart += ee;
        }
        WAVE_SYNC();                        // ee visible wave-wide
        #pragma unroll 2
        for(int j=0;j<clen;j++){
            unsigned o = (unsigned)__shfl((int)soff, j);
            unsigned pair = *(const unsigned*)(xb + o);
            #pragma unroll
            for(int h=0;h<8;h++){
                float wt = sh_ee[w][j][h];
                FMA_MIX_LO(acc0[h], pair, wt);
                FMA_MIX_HI(acc1[h], pair, wt);
            }
        }
    }
    dpart += __shfl_xor(dpart, 8);
    dpart += __shfl_xor(dpart, 16);
    dpart += __shfl_xor(dpart, 32);         // lane l holds denom for head l&7
    #pragma unroll
    for(int h=0;h<8;h++){
        float dn = __shfl(dpart, h) + 1e-16f;
        half2v o = { (_Float16)(acc0[h]/dn), (_Float16)(acc1[h]/dn) };
        *(half2v*)(oa + (size_t)node*F1 + h*128 + 2*l) = o;
    }
}

// gather loop with preloaded first group (chunk already has soff/ee in regs)
__device__ inline void agg_gather(const char* hb, unsigned soff, float ee, int clen,
                                  int g, uint4 v0, float w0, float* acc){
    int cpad = (clen + 3) & ~3;
    #pragma unroll 1
    for(int j0=0; j0<cpad; j0+=4){
        uint4 nv; float nw = 0.f;
        const bool more = (j0+4 < cpad);
        if(more){
            unsigned no = (unsigned)__shfl((int)soff, j0+4+g);
            nw = __shfl(ee, j0+4+g);
            nv = *(const uint4*)(hb + no);
        }
        fma_mix8(acc, v0, w0);
        if(more){ v0 = nv; w0 = nw; }
    }
}

// full chunk (loads its own state) — rare degree>64 tails. ROT: channel rotation of head slice.
__device__ inline void agg2_chunk(const char* hb, const float* asrc, const int* colsrc,
                                  int base, int clen, float rd, int h, int l, int g,
                                  float* acc, float& dpart){
    unsigned soff = 0; float eereg = 0.f;
    if(l < clen){
        int s = colsrc[base + l];
        soff = ((unsigned)s << 11) | ((unsigned)((h + s) & 7) << 8);
        float e = asrc[s*8 + h] + rd;
        e = (e > 0.f) ? e : 0.2f*e;
        eereg = expf(e);
        dpart += eereg;
    }
    unsigned o0 = (unsigned)__shfl((int)soff, g);
    float w0 = __shfl(eereg, g);
    uint4 v0 = *(const uint4*)(hb + o0);
    agg_gather(hb, soff, eereg, clen, g, v0, w0, acc);
}

__device__ inline void agg3_chunk(const char* hb, const float* asrc, const int* colsrc,
                                  int base, int clen, float rd, int chunk, int l, int g,
                                  float* acc, float& dpart){
    unsigned soff = 0; float eereg = 0.f;
    if(l < clen){
        int s = colsrc[base + l];
        soff = ((unsigned)s << 10) | ((unsigned)((chunk + s) & 3) << 8);
        float e = asrc[s] + rd;
        e = (e > 0.f) ? e : 0.2f*e;
        eereg = expf(e);
        dpart += eereg;
    }
    unsigned o0 = (unsigned)__shfl((int)soff, g);
    float w0 = __shfl(eereg, g);
    uint4 v0 = *(const uint4*)(hb + o0);
    agg_gather(hb, soff, eereg, clen, g, v0, w0, acc);
}

// ---------------- agg2: head-partitioned; channel-rotated h2 layout; 2 nodes/wave ----------------
// h2 physical layout: head slice h of node s lives at byte offset s*2048 + ((h+s)&7)*256.
// This spreads a fixed logical head's gathers across all 16 L2 channels (was 2/16).
__global__ __launch_bounds__(256) void agg2_kernel(const _Float16* __restrict__ hbuf,
                                                   const float* __restrict__ asrc,
                                                   const float* __restrict__ adst,
                                                   const int* __restrict__ rowp,
                                                   const int* __restrict__ colsrc,
                                                   const float* __restrict__ bias,
                                                   _Float16* __restrict__ oa){
    const int w = threadIdx.x >> 6, l = threadIdx.x & 63;
    const int h = blockIdx.x & 7;
    const int nA = (blockIdx.x >> 3)*8 + w*2;
    const int nB = nA + 1;
    const int g = l >> 4, i = l & 15;
    const char* hb = (const char*)hbuf + 16*i;

    // fused prologue: both nodes' chain-starts issued back-to-back
    int begA = rowp[nA], endA = rowp[nA+1];
    int begB = rowp[nB], endB = rowp[nB+1];
    float rdA = adst[nA*8 + h];
    float rdB = adst[nB*8 + h];
    int clenA = min(64, endA - begA);
    int clenB = min(64, endB - begB);
    int sA = (l < clenA) ? colsrc[begA + l] : 0;
    int sB = (l < clenB) ? colsrc[begB + l] : 0;
    unsigned soffA = 0, soffB = 0;
    float eeA = 0.f, eeB = 0.f;
    if(l < clenA){
        soffA = ((unsigned)sA << 11) | ((unsigned)((h + sA) & 7) << 8);
        float e = asrc[sA*8 + h] + rdA;
        e = (e > 0.f) ? e : 0.2f*e;
        eeA = expf(e);
    }
    if(l < clenB){
        soffB = ((unsigned)sB << 11) | ((unsigned)((h + sB) & 7) << 8);
        float e = asrc[sB*8 + h] + rdB;
        e = (e > 0.f) ? e : 0.2f*e;
        eeB = expf(e);
    }
    unsigned oA = (unsigned)__shfl((int)soffA, g);
    float wA = __shfl(eeA, g);
    uint4 vA = *(const uint4*)(hb + oA);
    unsigned oB = (unsigned)__shfl((int)soffB, g);
    float wB = __shfl(eeB, g);
    uint4 vB = *(const uint4*)(hb + oB);

    // ---- node A ----
    float accA[8];
    #pragma unroll
    for(int k=0;k<8;k++) accA[k]=0.f;
    float dpA = eeA;
    agg_gather(hb, soffA, eeA, clenA, g, vA, wA, accA);
    for(int base=begA+64; base<endA; base+=64)
        agg2_chunk(hb, asrc, colsrc, base, min(64, endA-base), rdA, h, l, g, accA, dpA);

    // ---- node B ----
    float accB[8];
    #pragma unroll
    for(int k=0;k<8;k++) accB[k]=0.f;
    float dpB = eeB;
    agg_gather(hb, soffB, eeB, clenB, g, vB, wB, accB);
    for(int base=begB+64; base<endB; base+=64)
        agg2_chunk(hb, asrc, colsrc, base, min(64, endB-base), rdB, h, l, g, accB, dpB);

    // reductions (interleaved — independent)
    #pragma unroll
    for(int k=0;k<8;k++){
        accA[k] += __shfl_xor(accA[k], 16);
        accA[k] += __shfl_xor(accA[k], 32);
        accB[k] += __shfl_xor(accB[k], 16);
        accB[k] += __shfl_xor(accB[k], 32);
    }
    #pragma unroll
    for(int off=1; off<64; off<<=1){
        dpA += __shfl_xor(dpA, off);
        dpB += __shfl_xor(dpB, off);
    }
    if(g == 0){
        const int f = h*128 + 8*i;
        float4 b0 = *(const float4*)(bias + f);
        float4 b1 = *(const float4*)(bias + f + 4);
        float bb[8] = {b0.x,b0.y,b0.z,b0.w, b1.x,b1.y,b1.z,b1.w};
        float dnA = dpA + 1e-16f, dnB = dpB + 1e-16f;
        half8 oA8, oB8;
        #pragma unroll
        for(int k=0;k<8;k++){
            oA8[k] = (_Float16)fmaxf(accA[k]/dnA + bb[k], 0.f);
            oB8[k] = (_Float16)fmaxf(accB[k]/dnB + bb[k], 0.f);
        }
        *(half8*)(oa + (size_t)nA*F1 + f) = oA8;
        *(half8*)(oa + (size_t)nB*F1 + f) = oB8;
    }
}

// ---------------- agg3: chunk-partitioned (H=1); channel-rotated h3 layout; 2 nodes/wave ----------------
// h3 physical layout: chunk slice c of node s lives at byte offset s*1024 + ((c+s)&3)*256.
__global__ __launch_bounds__(256) void agg3_kernel(const _Float16* __restrict__ hbuf,
                                                   const float* __restrict__ asrc,
                                                   const float* __restrict__ adst,
                                                   const int* __restrict__ rowp,
                                                   const int* __restrict__ colsrc,
                                                   const float* __restrict__ bias,
                                                   _Float16* __restrict__ oa){
    const int w = threadIdx.x >> 6, l = threadIdx.x & 63;
    const int i7 = blockIdx.x & 7;
    const int chunk = i7 & 3, sub = i7 >> 2;
    const int nA = ((blockIdx.x >> 3)*2 + sub)*8 + w*2;
    const int nB = nA + 1;
    const int g = l >> 4, i = l & 15;
    const char* hb = (const char*)hbuf + 16*i;

    int begA = rowp[nA], endA = rowp[nA+1];
    int begB = rowp[nB], endB = rowp[nB+1];
    float rdA = adst[nA];
    float rdB = adst[nB];
    int clenA = min(64, endA - begA);
    int clenB = min(64, endB - begB);
    int sA = (l < clenA) ? colsrc[begA + l] : 0;
    int sB = (l < clenB) ? colsrc[begB + l] : 0;
    unsigned soffA = 0, soffB = 0;
    float eeA = 0.f, eeB = 0.f;
    if(l < clenA){
        soffA = ((unsigned)sA << 10) | ((unsigned)((chunk + sA) & 3) << 8);
        float e = asrc[sA] + rdA;
        e = (e > 0.f) ? e : 0.2f*e;
        eeA = expf(e);
    }
    if(l < clenB){
        soffB = ((unsigned)sB << 10) | ((unsigned)((chunk + sB) & 3) << 8);
        float e = asrc[sB] + rdB;
        e = (e > 0.f) ? e : 0.2f*e;
        eeB = expf(e);
    }
    unsigned oA = (unsigned)__shfl((int)soffA, g);
    float wA = __shfl(eeA, g);
    uint4 vA = *(const uint4*)(hb + oA);
    unsigned oB = (unsigned)__shfl((int)soffB, g);
    float wB = __shfl(eeB, g);
    uint4 vB = *(const uint4*)(hb + oB);

    float accA[8];
    #pragma unroll
    for(int k=0;k<8;k++) accA[k]=0.f;
    float dpA = eeA;
    agg_gather(hb, soffA, eeA, clenA, g, vA, wA, accA);
    for(int base=begA+64; base<endA; base+=64)
        agg3_chunk(hb, asrc, colsrc, base, min(64, endA-base), rdA, chunk, l, g, accA, dpA);

    float accB[8];
    #pragma unroll
    for(int k=0;k<8;k++) accB[k]=0.f;
    float dpB = eeB;
    agg_gather(hb, soffB, eeB, clenB, g, vB, wB, accB);
    for(int base=begB+64; base<endB; base+=64)
        agg3_chunk(hb, asrc, colsrc, base, min(64, endB-base), rdB, chunk, l, g, accB, dpB);

    #pragma unroll
    for(int k=0;k<8;k++){
        accA[k] += __shfl_xor(accA[k], 16);
        accA[k] += __shfl_xor(accA[k], 32);
        accB[k] += __shfl_xor(accB[k], 16);
        accB[k] += __shfl_xor(accB[k], 32);
    }
    #pragma unroll
    for(int off=1; off<64; off<<=1){
        dpA += __shfl_xor(dpA, off);
        dpB += __shfl_xor(dpB, off);
    }
    if(g == 0){
        const int f = chunk*128 + 8*i;
        float4 b0 = *(const float4*)(bias + f);
        float4 b1 = *(const float4*)(bias + f + 4);
        float bb[8] = {b0.x,b0.y,b0.z,b0.w, b1.x,b1.y,b1.z,b1.w};
        float dnA = dpA + 1e-16f, dnB = dpB + 1e-16f;
        half8 oA8, oB8;
        #pragma unroll
        for(int k=0;k<8;k++){
            oA8[k] = (_Float16)fmaxf(accA[k]/dnA + bb[k], 0.f);
            oB8[k] = (_Float16)fmaxf(accB[k]/dnB + bb[k], 0.f);
        }
        *(half8*)(oa + (size_t)nA*INT_DIM + f) = oA8;
        *(half8*)(oa + (size_t)nB*INT_DIM + f) = oB8;
    }
}

// ---------------- single-pass fp16 MFMA GEMM, 8 waves (2x4), 128x128 tile, dbuf 2-phase ----------------
// ROTM: 0 = linear output; 7/3 = per-row rotation of 128-col groups (channel spread for gathers)
template<int FUSE, int ROTM>
__global__ __launch_bounds__(512, 4) void mfma16_gemm_kernel(
    const _Float16* __restrict__ A, int lda, int za,
    const _Float16* __restrict__ B, int ldb, int zb,
    const float* __restrict__ bias, _Float16* __restrict__ O,
    int ldc, int zc, int K, int gx)
{
    __shared__ _Float16 lA[2][128*32];   // 8 KB per buffer
    __shared__ _Float16 lB[2][128*32];
    const int tid  = threadIdx.x;
    const int lane = tid & 63;
    const int w    = tid >> 6;      // 0..7
    const int wm   = w >> 2;        // 0..1 (row half)
    const int wn   = w & 3;         // 0..3 (col quarter)
    const int z    = blockIdx.z;

    // XCD-bijective swizzle
    const int nwg = gridDim.x;
    const int q = nwg >> 3, r = nwg & 7;
    const int xcd = blockIdx.x & 7, idx = blockIdx.x >> 3;
    const int wgid = (xcd < r ? xcd*(q+1) : r*(q+1) + (xcd-r)*q) + idx;
    const int row0 = (wgid / gx) * 128, col0 = (wgid % gx) * 128;

    f32x4 acc[4][2];
    #pragma unroll
    for(int i=0;i<4;i++)
        #pragma unroll
        for(int j=0;j<2;j++) acc[i][j] = (f32x4){0.f,0.f,0.f,0.f};

    // staging: 512 lanes cover 128 rows x 4 slots of 16B; LDS slot written = tid&3
    const int rr1 = tid >> 2;                        // 0..127
    const int ss1 = (tid & 3) ^ ((rr1 >> 1) & 3);    // swizzled global slot
    const size_t aoff = (size_t)(row0 + rr1) * lda + (size_t)z*za + ss1 * 8;
    const size_t boff = (size_t)(col0 + rr1) * ldb + (size_t)z*zb + ss1 * 8;

    typedef __attribute__((address_space(3))) char lds_char;
    lds_char* dA = (lds_char*)(&lA[0][0]) + w*1024;
    lds_char* dB = (lds_char*)(&lB[0][0]) + w*1024;

    int arow[4], brow[2];
    const int slotx = ((lane >> 4) ^ ((lane >> 1) & 3)) << 4;
    #pragma unroll
    for(int i=0;i<4;i++)
        arow[i] = (wm*64 + i*16 + (lane & 15)) * 64 + slotx;
    #pragma unroll
    for(int j=0;j<2;j++)
        brow[j] = (wn*32 + j*16 + (lane & 15)) * 64 + slotx;

    #define GLDS(src, dst) __builtin_amdgcn_global_load_lds( \
        (__attribute__((address_space(1))) void*)(src), \
        (__attribute__((address_space(3))) void*)(dst), 16, 0, 0)
    GLDS(A + aoff, dA);
    GLDS(B + boff, dB);
    __syncthreads();

    #pragma unroll 1
    for(int k0 = 0, kb = 0; k0 < K; k0 += 32, kb ^= 1){
        if(k0 + 32 < K){
            const int nb = kb ^ 1;
            GLDS(A + aoff + k0 + 32, dA + nb*8192);
            GLDS(B + boff + k0 + 32, dB + nb*8192);
        }
        const char* pA = (const char*)(&lA[0][0]) + kb*8192;
        const char* pB = (const char*)(&lB[0][0]) + kb*8192;
        half8 af[4];
        #pragma unroll
        for(int i=0;i<4;i++) af[i] = *(const half8*)(pA + arow[i]);
        #pragma unroll
        for(int j=0;j<2;j++){
            half8 bf = *(const half8*)(pB + brow[j]);
            #pragma unroll
            for(int i=0;i<4;i++)
                acc[i][j] = __builtin_amdgcn_mfma_f32_16x16x32_f16(af[i], bf, acc[i][j], 0, 0, 0);
        }
        __syncthreads();
    }
    #undef GLDS

    // epilogue: C/D layout col=lane&15, row=(lane>>4)*4+reg; optional per-row 128-col-group rotation
    #pragma unroll
    for(int i=0;i<4;i++){
        const int rr = row0 + wm*64 + i*16 + ((lane >> 4) << 2);
        #pragma unroll
        for(int j=0;j<2;j++){
            const int gc = z*zc + col0 + wn*32 + j*16 + (lane & 15);
            float b = FUSE ? bias[gc] : 0.f;
            #pragma unroll
            for(int rg=0;rg<4;rg++){
                float v = acc[i][j][rg];
                if(FUSE) v = fmaxf(v + b, 0.f);
                const int node = rr + rg;
                int pc = gc;
                if(ROTM){
                    int grp = ((gc >> 7) + node) & ROTM;
                    pc = (gc & 127) | (grp << 7);
                }
                O[(size_t)node * ldc + pc] = (_Float16)v;
            }
        }
    }
}

// ---------------- alpha from fp16 h: H=8, C=128 (channel-rotated h2 layout) ----------------
__global__ __launch_bounds__(128) void alpha16_h8_kernel(const _Float16* __restrict__ hbuf,
                                                         const float* __restrict__ a_src,
                                                         const float* __restrict__ a_dst,
                                                         float* __restrict__ asrc, float* __restrict__ adst){
    int node = blockIdx.x;
    int t = threadIdx.x;          // 128 threads; logical features 8t..8t+7, head t>>4
    int head = t >> 4;
    int poff = (((head + node) & 7) << 7) + ((t & 15) << 3);   // rotated physical feature idx
    half8 v = *(const half8*)(hbuf + (size_t)node*F1 + poff);
    const float4* ap = (const float4*)(a_src + 8*t);
    const float4* dp = (const float4*)(a_dst + 8*t);
    float4 a0 = ap[0], a1 = ap[1];
    float4 d0 = dp[0], d1 = dp[1];
    float av[8] = {a0.x,a0.y,a0.z,a0.w, a1.x,a1.y,a1.z,a1.w};
    float dv[8] = {d0.x,d0.y,d0.z,d0.w, d1.x,d1.y,d1.z,d1.w};
    float ps = 0.f, pd = 0.f;
    #pragma unroll
    for(int k=0;k<8;k++){
        float f = (float)v[k];
        ps += f * av[k];
        pd += f * dv[k];
    }
    #pragma unroll
    for(int off=8; off; off>>=1){ ps += __shfl_down(ps, off); pd += __shfl_down(pd, off); }
    if((t & 15) == 0){
        asrc[(size_t)node*8 + head] = ps;
        adst[(size_t)node*8 + head] = pd;
    }
}

// ---------------- alpha from fp16 h: H=1, C=512 (channel-rotated h3 layout) ----------------
__global__ __launch_bounds__(128) void alpha16_h1_kernel(const _Float16* __restrict__ hbuf,
                                                         const float* __restrict__ a_src,
                                                         const float* __restrict__ a_dst,
                                                         float* __restrict__ asrc, float* __restrict__ adst){
    int node = blockIdx.x;
    int t = threadIdx.x;          // 128 threads; logical features 4t..4t+3; chunk = t>>5
    int chunk = t >> 5;
    int poff = (((chunk + node) & 3) << 7) + ((t & 31) << 2);
    half4 v = *(const half4*)(hbuf + (size_t)node*INT_DIM + poff);
    float4 a = ((const float4*)a_src)[t];
    float4 d = ((const float4*)a_dst)[t];
    float ps = (float)v[0]*a.x + (float)v[1]*a.y + (float)v[2]*a.z + (float)v[3]*a.w;
    float pd = (float)v[0]*d.x + (float)v[1]*d.y + (float)v[2]*d.z + (float)v[3]*d.w;
    #pragma unroll
    for(int off=32; off; off>>=1){ ps += __shfl_down(ps, off); pd += __shfl_down(pd, off); }
    __shared__ float shs[2], shd[2];
    int wv = t >> 6;
    if((t & 63) == 0){ shs[wv] = ps; shd[wv] = pd; }
    __syncthreads();
    if(t == 0){
        asrc[node] = shs[0] + shs[1];
        adst[node] = shd[0] + shd[1];
    }
}

// ---------------- classifier: out[n,3] = h16[n,:512] @ Wc + bc ----------------
__global__ __launch_bounds__(256) void cls16_kernel(const _Float16* __restrict__ h, const float* __restrict__ Wc,
                                                    const float* __restrict__ bc, float* __restrict__ out, int n){
    int node = blockIdx.x*4 + (threadIdx.x >> 6);
    int lane = threadIdx.x & 63;
    if(node >= n) return;
    half8 v = ((const half8*)(h + (size_t)node*INT_DIM))[lane];  // features 8l..8l+7
    float s0=0.f, s1=0.f, s2=0.f;
    #pragma unroll
    for(int k=0;k<8;k++){
        float f = (float)v[k];
        const float* wr = Wc + (8*lane + k)*3;
        s0 += f * wr[0];
        s1 += f * wr[1];
        s2 += f * wr[2];
    }
    #pragma unroll
    for(int off=32; off; off>>=1){
        s0 += __shfl_down(s0, off);
        s1 += __shfl_down(s1, off);
        s2 += __shfl_down(s2, off);
    }
    if(lane==0){
        out[(size_t)node*3+0] = s0 + bc[0];
        out[(size_t)node*3+1] = s1 + bc[1];
        out[(size_t)node*3+2] = s2 + bc[2];
    }
}

extern "C" void kernel_launch(void* const* d_in, const int* in_sizes, int n_in,
                              void* d_out, int out_size, void* d_ws, size_t ws_size,
                              hipStream_t stream){
    const float* x      = (const float*)d_in[0];
    const int*   ei     = (const int*)d_in[1];
    const float* W1     = (const float*)d_in[2];
    const float* a_src1 = (const float*)d_in[3];
    const float* a_dst1 = (const float*)d_in[4];
    const float* b1     = (const float*)d_in[5];
    const float* W2     = (const float*)d_in[6];
    const float* a_src2 = (const float*)d_in[7];
    const float* a_dst2 = (const float*)d_in[8];
    const float* b2     = (const float*)d_in[9];
    const float* W3     = (const float*)d_in[10];
    const float* a_src3 = (const float*)d_in[11];
    const float* a_dst3 = (const float*)d_in[12];
    const float* b3     = (const float*)d_in[13];
    const float* Wl     = (const float*)d_in[14];
    const float* bl     = (const float*)d_in[15];
    const float* Wc     = (const float*)d_in[16];
    const float* bc     = (const float*)d_in[17];
    float* out = (float*)d_out;

    const int* src = ei;
    const int* dst = ei + EE;

    // workspace carve: two 41.4MB regions; hA/hB (fp16, 20.7MB each) use the lower halves,
    // weights + x16 live in regA's free upper half.
    char* p = (char*)d_ws;
    char* regA = p;  p += (size_t)MPAD*F1*4;
    char* regB = p;  p += (size_t)MPAD*F1*4;
    float* aw1  = (float*)p;  p += 16*IN_DIM*4;
    float* asrc = (float*)p;  p += (size_t)NN*HEADS*4;
    float* adst = (float*)p;  p += (size_t)NN*HEADS*4;
    int* cnt    = (int*)p;    p += NN*4;
    int* rowp   = (int*)p;    p += (NN+1)*4;
    int* cursor = (int*)p;    p += NN*4;
    int* colsrc = (int*)p;    p += EE*4;

    _Float16* hA = (_Float16*)regA;      // xa -> h2 -> h3 -> lin
    _Float16* hB = (_Float16*)regB;      // out1 -> out2 -> out3
    _Float16* up   = (_Float16*)(regA + (size_t)MPAD*F1*2);   // free upper half of regA
    _Float16* tW1  = up;                        // 1024*128
    _Float16* tW2  = tW1 + (size_t)F1*IN_DIM;   // 1024*1024
    _Float16* tW3  = tW2 + (size_t)F1*F1;       // 512*1024
    _Float16* tWl  = tW3 + (size_t)INT_DIM*F1;  // 512*512
    _Float16* x16  = tWl + (size_t)INT_DIM*INT_DIM;  // 10000*128

    // ---- fused prep (weights/x16/aw1/cnt-zero) + CSR build + alpha1 ----
    prep_kernel<<<3188, 256, 0, stream>>>(W1, W2, W3, Wl, x, a_src1, a_dst1,
                                          tW1, tW2, tW3, tWl, x16, aw1, cnt);
    count_alpha1_kernel<<<1250, 256, 0, stream>>>(dst, cnt, x, aw1, asrc, adst);
    scan_kernel<<<1, 1024, 0, stream>>>(cnt, rowp, cursor, NN);
    fill_kernel<<<(EE+255)/256, 256, 0, stream>>>(src, dst, EE, cursor, colsrc);

    // ---- Layer 1 (agg-first via linearity) ----
    agg1_kernel<<<NN/4, 256, 0, stream>>>(x16, asrc, adst, rowp, colsrc, hA);
    mfma16_gemm_kernel<1,0><<<dim3(MPAD/128, 1, HEADS), 512, 0, stream>>>(
        hA, F1, 128,  tW1, IN_DIM, 128*IN_DIM,
        b1, hB, F1, 128,  IN_DIM, 1);

    // ---- Layer 2 (project-first, fp16; h2 stored channel-rotated) ----
    mfma16_gemm_kernel<0,7><<<dim3((F1/128)*(MPAD/128), 1, 1), 512, 0, stream>>>(
        hB, F1, 0,  tW2, F1, 0,
        nullptr, hA, F1, 0,  F1, F1/128);
    alpha16_h8_kernel<<<NN, 128, 0, stream>>>(hA, a_src2, a_dst2, asrc, adst);
    agg2_kernel<<<(NN/8)*8, 256, 0, stream>>>(hA, asrc, adst, rowp, colsrc, b2, hB);

    // ---- Layer 3 (project-first, H=1, fp16; h3 stored channel-rotated) ----
    mfma16_gemm_kernel<0,3><<<dim3((INT_DIM/128)*(MPAD/128), 1, 1), 512, 0, stream>>>(
        hB, F1, 0,  tW3, F1, 0,
        nullptr, hA, INT_DIM, 0,  F1, INT_DIM/128);
    alpha16_h1_kernel<<<NN, 128, 0, stream>>>(hA, a_src3, a_dst3, asrc, adst);
    agg3_kernel<<<(NN/16)*8, 256, 0, stream>>>(hA, asrc, adst, rowp, colsrc, b3, hB);

    // ---- Linear: relu(out3 @ Wl + bl) -> hA fp16 [NN,512] ----
    mfma16_gemm_kernel<1,0><<<dim3((INT_DIM/128)*(MPAD/128), 1, 1), 512, 0, stream>>>(
        hB, INT_DIM, 0,  tWl, INT_DIM, 0,
        bl, hA, INT_DIM, 0,  INT_DIM, INT_DIM/128);

    // ---- Classifier ----
    cls16_kernel<<<(NN+3)/4, 256, 0, stream>>>(hA, Wc, bc, out, NN);
}

// Round 19
// 246.696 us; speedup vs baseline: 1.0138x; 1.0138x over previous
//
#include <hip/hip_runtime.h>
#include <hip/hip_bf16.h>

// Problem constants
#define NN 10000
#define EE 160000
#define IN_DIM 128
#define HID 128
#define HEADS 8
#define F1 (HEADS*HID)   // 1024
#define INT_DIM 512
#define OUT_DIM 3
#define MPAD 10112       // 79 * 128

typedef __attribute__((ext_vector_type(4))) float f32x4;
typedef __attribute__((ext_vector_type(8))) _Float16 half8;
typedef __attribute__((ext_vector_type(4))) _Float16 half4;
typedef __attribute__((ext_vector_type(2))) _Float16 half2v;

// wave-local LDS fence: wait all this wave's DS ops, and pin program order
#define WAVE_SYNC() do { asm volatile("s_waitcnt lgkmcnt(0)" ::: "memory"); \
                         __builtin_amdgcn_sched_barrier(0); } while(0)

// fp32 acc += f32(w) * f16-half-of(pair)  — v_fma_mix_f32, no separate cvt
#define FMA_MIX_LO(acc, pair, w) asm("v_fma_mix_f32 %0, %1, %2, %0 op_sel:[0,0,0] op_sel_hi:[1,0,0]" \
                                     : "+v"(acc) : "v"(pair), "v"(w))
#define FMA_MIX_HI(acc, pair, w) asm("v_fma_mix_f32 %0, %1, %2, %0 op_sel:[1,0,0] op_sel_hi:[1,0,0]" \
                                     : "+v"(acc) : "v"(pair), "v"(w))

// ---------------- CSR build ----------------
// single-pass 1024-thread scan: 10 elems/thread serial + shfl wave-scan + cross-wave
__global__ __launch_bounds__(1024) void scan_kernel(const int* __restrict__ cnt, int* __restrict__ rowp,
                                                    int* __restrict__ cursor, int n){
    int t = threadIdx.x;
    int base = t*10;
    int vals[10];
    int run = 0;
    #pragma unroll
    for(int k=0;k<10;k++){
        int i = base+k;
        int v = (i<n) ? cnt[i] : 0;
        vals[k] = run;           // exclusive within thread
        run += v;
    }
    int lane = t & 63, wv = t >> 6;
    int inc = run;               // inclusive wave scan of thread totals
    #pragma unroll
    for(int off=1; off<64; off<<=1){
        int u = __shfl_up(inc, off);
        if(lane >= off) inc += u;
    }
    __shared__ int wtot[16], woff[16];
    if(lane == 63) wtot[wv] = inc;
    __syncthreads();
    if(t < 16){
        int v = wtot[t];
        int inc2 = v;
        #pragma unroll
        for(int off=1; off<16; off<<=1){
            int u = __shfl_up(inc2, off);
            if(t >= off) inc2 += u;
        }
        woff[t] = inc2 - v;      // exclusive wave offset
    }
    __syncthreads();
    int thread_excl = woff[wv] + inc - run;
    #pragma unroll
    for(int k=0;k<10;k++){
        int i = base+k;
        if(i<n){
            int v = thread_excl + vals[k];
            rowp[i] = v;
            cursor[i] = v;
        }
    }
    if(t == 1023) rowp[n] = thread_excl + run;
}

__global__ __launch_bounds__(256) void fill_kernel(const int* __restrict__ src, const int* __restrict__ dst,
                                                   int E, int* __restrict__ cursor, int* __restrict__ colsrc){
    int e = blockIdx.x*256 + threadIdx.x;
    if(e < E){
        int d = dst[e];
        int pos = atomicAdd(&cursor[d], 1);
        colsrc[pos] = src[e];
    }
}

// ---------------- fused prep: 4 weight transposes + x->fp16 + aw1 + cnt zero ----------------
__device__ inline void transpose_tile16(const float* __restrict__ B, _Float16* __restrict__ T,
                                        int K, int N, int idx){
    __shared__ float tile[32][33];
    const int tx = threadIdx.x & 31, ty = threadIdx.x >> 5;   // 32 x 8
    const int gx = N >> 5;
    const int n0 = (idx % gx) * 32, k0 = (idx / gx) * 32;
    #pragma unroll
    for(int i = 0; i < 32; i += 8)
        tile[ty + i][tx] = B[(size_t)(k0 + ty + i) * N + n0 + tx];
    __syncthreads();
    #pragma unroll
    for(int i = 0; i < 32; i += 8){
        int nn = ty + i;
        T[(size_t)(n0 + nn) * K + k0 + tx] = (_Float16)tile[tx][nn];
    }
}

__global__ __launch_bounds__(256) void prep_kernel(
    const float* __restrict__ W1, const float* __restrict__ W2,
    const float* __restrict__ W3, const float* __restrict__ Wl,
    const float* __restrict__ x,
    const float* __restrict__ a_src1, const float* __restrict__ a_dst1,
    _Float16* __restrict__ tW1, _Float16* __restrict__ tW2,
    _Float16* __restrict__ tW3, _Float16* __restrict__ tWl,
    _Float16* __restrict__ x16, float* __restrict__ aw,
    int* __restrict__ cnt)
{
    int b = blockIdx.x;
    if(b < 128){            transpose_tile16(W1, tW1, IN_DIM, F1, b); }
    else if(b < 1152){      transpose_tile16(W2, tW2, F1, F1, b-128); }
    else if(b < 1664){      transpose_tile16(W3, tW3, F1, INT_DIM, b-1152); }
    else if(b < 1920){      transpose_tile16(Wl, tWl, INT_DIM, INT_DIM, b-1664); }
    else if(b < 3170){
        int i = (b-1920)*256 + threadIdx.x;     // < 320000 exactly
        float4 v = ((const float4*)x)[i];
        half4 o = { (_Float16)v.x, (_Float16)v.y, (_Float16)v.z, (_Float16)v.w };
        ((half4*)x16)[i] = o;
    }
    else if(b < 3178){
        int idx = (b-3170)*256 + threadIdx.x;
        if(idx < 16*IN_DIM){
            int j = idx >> 7, k = idx & 127;
            int hj = j & 7;
            const float* av = (j < 8 ? a_src1 : a_dst1) + hj*HID;
            const float* wr = W1 + (size_t)k*F1 + hj*HID;
            float s = 0.f;
            #pragma unroll 4
            for(int c = 0; c < HID; c++) s += av[c] * wr[c];
            aw[idx] = s;
        }
    }
    else {
        int i = (b-3178)*1024 + threadIdx.x*4;
        if(i < NN) *(int4*)(cnt + i) = (int4){0,0,0,0};   // NN%4==0
    }
}

// ---------------- fused: count (blocks 0..624) + alpha1 (blocks 625..1249) ----------------
__global__ __launch_bounds__(256) void count_alpha1_kernel(
    const int* __restrict__ dst, int* __restrict__ cnt,
    const float* __restrict__ x, const float* __restrict__ aw,
    float* __restrict__ asrc, float* __restrict__ adst)
{
    int b = blockIdx.x;
    if(b < 625){
        int e = b*256 + threadIdx.x;
        if(e < EE) atomicAdd(&cnt[dst[e]], 1);
        return;
    }
    __shared__ float xs[16][128];
    __shared__ float aws[16][128];
    int t = threadIdx.x;
    int nb = (b - 625) * 16;
    for(int i = t; i < 16*128; i += 256){
        xs[i >> 7][i & 127] = x[(size_t)nb*128 + i];
        aws[i >> 7][i & 127] = aw[i];
    }
    __syncthreads();
    int nl = t >> 4, j = t & 15;
    float s = 0.f;
    #pragma unroll 4
    for(int c = 0; c < 128; c++) s += xs[nl][c] * aws[j][c];
    int node = nb + nl;
    if(j < 8) asrc[node*8 + j] = s;
    else      adst[node*8 + (j-8)] = s;
}

// ---------------- agg1: per-head softmax-agg of fp16 x; 4 nodes/block, 1 wave/node; emits fp16 ----------------
__global__ __launch_bounds__(256) void agg1_kernel(const _Float16* __restrict__ x16,
                                                   const float* __restrict__ asrc,
                                                   const float* __restrict__ adst,
                                                   const int* __restrict__ rowp,
                                                   const int* __restrict__ colsrc,
                                                   _Float16* __restrict__ oa){
    const int w = threadIdx.x >> 6, l = threadIdx.x & 63;
    const int node = blockIdx.x*4 + w;
    __shared__ float sh_ee[4][64][8];
    int beg = rowp[node], end = rowp[node+1];
    float rd = adst[node*8 + (l & 7)];
    float acc0[8], acc1[8];
    #pragma unroll
    for(int h=0;h<8;h++){ acc0[h]=0.f; acc1[h]=0.f; }
    float dpart = 0.f;
    const char* xb = (const char*)x16 + 4*l;
    for(int base=beg; base<end; base+=64){
        int clen = min(64, end-base);
        WAVE_SYNC();                        // prior chunk's ee reads complete
        unsigned soff = 0;
        if(l < clen) soff = (unsigned)colsrc[base + l] << 8;   // row byte offset (256B rows)
        for(int it=l; it<clen*8; it+=64){
            int j = it >> 3;
            int s = colsrc[base + j];
            float e = asrc[s*8 + (l & 7)] + rd;
            e = (e > 0.f) ? e : 0.2f*e;
            float ee = expf(e);
            sh_ee[w][j][l & 7] = ee;
            dpart += ee;
        }
        WAVE_SYNC();                        // ee visible wave-wide
        #pragma unroll 2
        for(int j=0;j<clen;j++){
            unsigned o = (unsigned)__shfl((int)soff, j);
            unsigned pair = *(const unsigned*)(xb + o);
            #pragma unroll
            for(int h=0;h<8;h++){
                float wt = sh_ee[w][j][h];
                FMA_MIX_LO(acc0[h], pair, wt);
                FMA_MIX_HI(acc1[h], pair, wt);
            }
        }
    }
    dpart += __shfl_xor(dpart, 8);
    dpart += __shfl_xor(dpart, 16);
    dpart += __shfl_xor(dpart, 32);         // lane l holds denom for head l&7
    #pragma unroll
    for(int h=0;h<8;h++){
        float dn = __shfl(dpart, h) + 1e-16f;
        half2v o = { (_Float16)(acc0[h]/dn), (_Float16)(acc1[h]/dn) };
        *(half2v*)(oa + (size_t)node*F1 + h*128 + 2*l) = o;
    }
}

// ---------------- agg2: head-partitioned gather; 16-lane group per edge; fma_mix + 32-bit addr ----------------
__global__ __launch_bounds__(256) void agg2_kernel(const _Float16* __restrict__ hbuf,
                                                   const float* __restrict__ asrc,
                                                   const float* __restrict__ adst,
                                                   const int* __restrict__ rowp,
                                                   const int* __restrict__ colsrc,
                                                   const float* __restrict__ bias,
                                                   _Float16* __restrict__ oa){
    const int w = threadIdx.x >> 6, l = threadIdx.x & 63;
    const int h = blockIdx.x & 7;
    const int node = (blockIdx.x >> 3)*4 + w;
    const int g = l >> 4, i = l & 15;    // group g -> edge j0+g; lane i -> features 8i..8i+7
    int beg = rowp[node], end = rowp[node+1];
    float rd = adst[node*8 + h];
    float acc[8];
    #pragma unroll
    for(int k=0;k<8;k++) acc[k]=0.f;
    float dpart = 0.f;
    const char* hb = (const char*)hbuf + h*256 + 16*i;
    for(int base=beg; base<end; base+=64){
        int clen = min(64, end-base);
        unsigned soff = 0; float eereg = 0.f;
        if(l < clen){
            int s = colsrc[base + l];
            soff = (unsigned)s << 11;        // row byte offset (2048B rows)
            float e = asrc[s*8 + h] + rd;
            e = (e > 0.f) ? e : 0.2f*e;
            eereg = expf(e);
            dpart += eereg;
        }
        int cpad = (clen + 3) & ~3;
        unsigned o0 = (unsigned)__shfl((int)soff, g);
        float w0 = __shfl(eereg, g);
        uint4 v0 = *(const uint4*)(hb + o0);
        #pragma unroll 1
        for(int j0=0; j0<cpad; j0+=4){
            uint4 nv; float nw = 0.f;
            const bool more = (j0+4 < cpad);
            if(more){
                unsigned no = (unsigned)__shfl((int)soff, j0+4+g);
                nw = __shfl(eereg, j0+4+g);
                nv = *(const uint4*)(hb + no);
            }
            FMA_MIX_LO(acc[0], v0.x, w0);  FMA_MIX_HI(acc[1], v0.x, w0);
            FMA_MIX_LO(acc[2], v0.y, w0);  FMA_MIX_HI(acc[3], v0.y, w0);
            FMA_MIX_LO(acc[4], v0.z, w0);  FMA_MIX_HI(acc[5], v0.z, w0);
            FMA_MIX_LO(acc[6], v0.w, w0);  FMA_MIX_HI(acc[7], v0.w, w0);
            if(more){ v0 = nv; w0 = nw; }
        }
    }
    #pragma unroll
    for(int k=0;k<8;k++){
        acc[k] += __shfl_xor(acc[k], 16);
        acc[k] += __shfl_xor(acc[k], 32);
    }
    #pragma unroll
    for(int off=1; off<64; off<<=1) dpart += __shfl_xor(dpart, off);
    float dn = dpart + 1e-16f;
    if(g == 0){
        const int f = h*128 + 8*i;
        float4 b0 = *(const float4*)(bias + f);
        float4 b1 = *(const float4*)(bias + f + 4);
        float bb[8] = {b0.x,b0.y,b0.z,b0.w, b1.x,b1.y,b1.z,b1.w};
        half8 o;
        #pragma unroll
        for(int k=0;k<8;k++)
            o[k] = (_Float16)fmaxf(acc[k]/dn + bb[k], 0.f);
        *(half8*)(oa + (size_t)node*F1 + f) = o;
    }
}

// ---------------- agg3: chunk-partitioned gather (H=1); 16-lane group per edge; fma_mix ----------------
__global__ __launch_bounds__(256) void agg3_kernel(const _Float16* __restrict__ hbuf,
                                                   const float* __restrict__ asrc,
                                                   const float* __restrict__ adst,
                                                   const int* __restrict__ rowp,
                                                   const int* __restrict__ colsrc,
                                                   const float* __restrict__ bias,
                                                   _Float16* __restrict__ oa){
    const int w = threadIdx.x >> 6, l = threadIdx.x & 63;
    const int i7 = blockIdx.x & 7;
    const int chunk = i7 & 3, sub = i7 >> 2;
    const int node = ((blockIdx.x >> 3)*2 + sub)*4 + w;
    const int g = l >> 4, i = l & 15;
    int beg = rowp[node], end = rowp[node+1];
    float rd = adst[node];
    float acc[8];
    #pragma unroll
    for(int k=0;k<8;k++) acc[k]=0.f;
    float dpart = 0.f;
    const char* hb = (const char*)hbuf + chunk*256 + 16*i;
    for(int base=beg; base<end; base+=64){
        int clen = min(64, end-base);
        unsigned soff = 0; float eereg = 0.f;
        if(l < clen){
            int s = colsrc[base + l];
            soff = (unsigned)s << 10;        // row byte offset (1024B rows)
            float e = asrc[s] + rd;
            e = (e > 0.f) ? e : 0.2f*e;
            eereg = expf(e);
            dpart += eereg;
        }
        int cpad = (clen + 3) & ~3;
        unsigned o0 = (unsigned)__shfl((int)soff, g);
        float w0 = __shfl(eereg, g);
        uint4 v0 = *(const uint4*)(hb + o0);
        #pragma unroll 1
        for(int j0=0; j0<cpad; j0+=4){
            uint4 nv; float nw = 0.f;
            const bool more = (j0+4 < cpad);
            if(more){
                unsigned no = (unsigned)__shfl((int)soff, j0+4+g);
                nw = __shfl(eereg, j0+4+g);
                nv = *(const uint4*)(hb + no);
            }
            FMA_MIX_LO(acc[0], v0.x, w0);  FMA_MIX_HI(acc[1], v0.x, w0);
            FMA_MIX_LO(acc[2], v0.y, w0);  FMA_MIX_HI(acc[3], v0.y, w0);
            FMA_MIX_LO(acc[4], v0.z, w0);  FMA_MIX_HI(acc[5], v0.z, w0);
            FMA_MIX_LO(acc[6], v0.w, w0);  FMA_MIX_HI(acc[7], v0.w, w0);
            if(more){ v0 = nv; w0 = nw; }
        }
    }
    #pragma unroll
    for(int k=0;k<8;k++){
        acc[k] += __shfl_xor(acc[k], 16);
        acc[k] += __shfl_xor(acc[k], 32);
    }
    #pragma unroll
    for(int off=1; off<64; off<<=1) dpart += __shfl_xor(dpart, off);
    float dn = dpart + 1e-16f;
    if(g == 0){
        const int f = chunk*128 + 8*i;
        float4 b0 = *(const float4*)(bias + f);
        float4 b1 = *(const float4*)(bias + f + 4);
        float bb[8] = {b0.x,b0.y,b0.z,b0.w, b1.x,b1.y,b1.z,b1.w};
        half8 o;
        #pragma unroll
        for(int k=0;k<8;k++)
            o[k] = (_Float16)fmaxf(acc[k]/dn + bb[k], 0.f);
        *(half8*)(oa + (size_t)node*INT_DIM + f) = o;
    }
}

// ---------------- single-pass fp16 MFMA GEMM, 8 waves (2x4), 128x128 tile, dbuf 2-phase ----------------
template<int FUSE>
__global__ __launch_bounds__(512, 4) void mfma16_gemm_kernel(
    const _Float16* __restrict__ A, int lda, int za,
    const _Float16* __restrict__ B, int ldb, int zb,
    const float* __restrict__ bias, _Float16* __restrict__ O,
    int ldc, int zc, int K, int gx)
{
    __shared__ _Float16 lA[2][128*32];   // 8 KB per buffer
    __shared__ _Float16 lB[2][128*32];
    const int tid  = threadIdx.x;
    const int lane = tid & 63;
    const int w    = tid >> 6;      // 0..7
    const int wm   = w >> 2;        // 0..1 (row half)
    const int wn   = w & 3;         // 0..3 (col quarter)
    const int z    = blockIdx.z;

    // XCD-bijective swizzle
    const int nwg = gridDim.x;
    const int q = nwg >> 3, r = nwg & 7;
    const int xcd = blockIdx.x & 7, idx = blockIdx.x >> 3;
    const int wgid = (xcd < r ? xcd*(q+1) : r*(q+1) + (xcd-r)*q) + idx;
    const int row0 = (wgid / gx) * 128, col0 = (wgid % gx) * 128;

    f32x4 acc[4][2];
    #pragma unroll
    for(int i=0;i<4;i++)
        #pragma unroll
        for(int j=0;j<2;j++) acc[i][j] = (f32x4){0.f,0.f,0.f,0.f};

    // staging: 512 lanes cover 128 rows x 4 slots of 16B; LDS slot written = tid&3
    const int rr1 = tid >> 2;                        // 0..127
    const int ss1 = (tid & 3) ^ ((rr1 >> 1) & 3);    // swizzled global slot
    const size_t aoff = (size_t)(row0 + rr1) * lda + (size_t)z*za + ss1 * 8;
    const size_t boff = (size_t)(col0 + rr1) * ldb + (size_t)z*zb + ss1 * 8;

    typedef __attribute__((address_space(3))) char lds_char;
    lds_char* dA = (lds_char*)(&lA[0][0]) + w*1024;
    lds_char* dB = (lds_char*)(&lB[0][0]) + w*1024;

    int arow[4], brow[2];
    const int slotx = ((lane >> 4) ^ ((lane >> 1) & 3)) << 4;
    #pragma unroll
    for(int i=0;i<4;i++)
        arow[i] = (wm*64 + i*16 + (lane & 15)) * 64 + slotx;
    #pragma unroll
    for(int j=0;j<2;j++)
        brow[j] = (wn*32 + j*16 + (lane & 15)) * 64 + slotx;

    #define GLDS(src, dst) __builtin_amdgcn_global_load_lds( \
        (__attribute__((address_space(1))) void*)(src), \
        (__attribute__((address_space(3))) void*)(dst), 16, 0, 0)
    GLDS(A + aoff, dA);
    GLDS(B + boff, dB);
    __syncthreads();

    #pragma unroll 1
    for(int k0 = 0, kb = 0; k0 < K; k0 += 32, kb ^= 1){
        if(k0 + 32 < K){
            const int nb = kb ^ 1;
            GLDS(A + aoff + k0 + 32, dA + nb*8192);
            GLDS(B + boff + k0 + 32, dB + nb*8192);
        }
        const char* pA = (const char*)(&lA[0][0]) + kb*8192;
        const char* pB = (const char*)(&lB[0][0]) + kb*8192;
        half8 af[4];
        #pragma unroll
        for(int i=0;i<4;i++) af[i] = *(const half8*)(pA + arow[i]);
        #pragma unroll
        for(int j=0;j<2;j++){
            half8 bf = *(const half8*)(pB + brow[j]);
            #pragma unroll
            for(int i=0;i<4;i++)
                acc[i][j] = __builtin_amdgcn_mfma_f32_16x16x32_f16(af[i], bf, acc[i][j], 0, 0, 0);
        }
        __syncthreads();
    }
    #undef GLDS

    // epilogue: C/D layout col=lane&15, row=(lane>>4)*4+reg
    #pragma unroll
    for(int i=0;i<4;i++){
        const int rr = row0 + wm*64 + i*16 + ((lane >> 4) << 2);
        #pragma unroll
        for(int j=0;j<2;j++){
            const int gc = z*zc + col0 + wn*32 + j*16 + (lane & 15);
            float b = FUSE ? bias[gc] : 0.f;
            #pragma unroll
            for(int rg=0;rg<4;rg++){
                float v = acc[i][j][rg];
                if(FUSE) v = fmaxf(v + b, 0.f);
                O[(size_t)(rr + rg) * ldc + gc] = (_Float16)v;
            }
        }
    }
}

// ---------------- alpha from fp16 h: H=8, C=128 ----------------
__global__ __launch_bounds__(128) void alpha16_h8_kernel(const _Float16* __restrict__ hbuf,
                                                         const float* __restrict__ a_src,
                                                         const float* __restrict__ a_dst,
                                                         float* __restrict__ asrc, float* __restrict__ adst){
    int node = blockIdx.x;
    int t = threadIdx.x;          // 128 threads; features 8t..8t+7, head t>>4
    half8 v = ((const half8*)(hbuf + (size_t)node*F1))[t];
    const float4* ap = (const float4*)(a_src + 8*t);
    const float4* dp = (const float4*)(a_dst + 8*t);
    float4 a0 = ap[0], a1 = ap[1];
    float4 d0 = dp[0], d1 = dp[1];
    float av[8] = {a0.x,a0.y,a0.z,a0.w, a1.x,a1.y,a1.z,a1.w};
    float dv[8] = {d0.x,d0.y,d0.z,d0.w, d1.x,d1.y,d1.z,d1.w};
    float ps = 0.f, pd = 0.f;
    #pragma unroll
    for(int k=0;k<8;k++){
        float f = (float)v[k];
        ps += f * av[k];
        pd += f * dv[k];
    }
    #pragma unroll
    for(int off=8; off; off>>=1){ ps += __shfl_down(ps, off); pd += __shfl_down(pd, off); }
    if((t & 15) == 0){
        asrc[(size_t)node*8 + (t>>4)] = ps;
        adst[(size_t)node*8 + (t>>4)] = pd;
    }
}

// ---------------- alpha from fp16 h: H=1, C=512 ----------------
__global__ __launch_bounds__(128) void alpha16_h1_kernel(const _Float16* __restrict__ hbuf,
                                                         const float* __restrict__ a_src,
                                                         const float* __restrict__ a_dst,
                                                         float* __restrict__ asrc, float* __restrict__ adst){
    int node = blockIdx.x;
    int t = threadIdx.x;          // 128 threads; features 4t..4t+3
    half4 v = ((const half4*)(hbuf + (size_t)node*INT_DIM))[t];
    float4 a = ((const float4*)a_src)[t];
    float4 d = ((const float4*)a_dst)[t];
    float ps = (float)v[0]*a.x + (float)v[1]*a.y + (float)v[2]*a.z + (float)v[3]*a.w;
    float pd = (float)v[0]*d.x + (float)v[1]*d.y + (float)v[2]*d.z + (float)v[3]*d.w;
    #pragma unroll
    for(int off=32; off; off>>=1){ ps += __shfl_down(ps, off); pd += __shfl_down(pd, off); }
    __shared__ float shs[2], shd[2];
    int wv = t >> 6;
    if((t & 63) == 0){ shs[wv] = ps; shd[wv] = pd; }
    __syncthreads();
    if(t == 0){
        asrc[node] = shs[0] + shs[1];
        adst[node] = shd[0] + shd[1];
    }
}

// ---------------- classifier: out[n,3] = h16[n,:512] @ Wc + bc ----------------
__global__ __launch_bounds__(256) void cls16_kernel(const _Float16* __restrict__ h, const float* __restrict__ Wc,
                                                    const float* __restrict__ bc, float* __restrict__ out, int n){
    int node = blockIdx.x*4 + (threadIdx.x >> 6);
    int lane = threadIdx.x & 63;
    if(node >= n) return;
    half8 v = ((const half8*)(h + (size_t)node*INT_DIM))[lane];  // features 8l..8l+7
    float s0=0.f, s1=0.f, s2=0.f;
    #pragma unroll
    for(int k=0;k<8;k++){
        float f = (float)v[k];
        const float* wr = Wc + (8*lane + k)*3;
        s0 += f * wr[0];
        s1 += f * wr[1];
        s2 += f * wr[2];
    }
    #pragma unroll
    for(int off=32; off; off>>=1){
        s0 += __shfl_down(s0, off);
        s1 += __shfl_down(s1, off);
        s2 += __shfl_down(s2, off);
    }
    if(lane==0){
        out[(size_t)node*3+0] = s0 + bc[0];
        out[(size_t)node*3+1] = s1 + bc[1];
        out[(size_t)node*3+2] = s2 + bc[2];
    }
}

extern "C" void kernel_launch(void* const* d_in, const int* in_sizes, int n_in,
                              void* d_out, int out_size, void* d_ws, size_t ws_size,
                              hipStream_t stream){
    const float* x      = (const float*)d_in[0];
    const int*   ei     = (const int*)d_in[1];
    const float* W1     = (const float*)d_in[2];
    const float* a_src1 = (const float*)d_in[3];
    const float* a_dst1 = (const float*)d_in[4];
    const float* b1     = (const float*)d_in[5];
    const float* W2     = (const float*)d_in[6];
    const float* a_src2 = (const float*)d_in[7];
    const float* a_dst2 = (const float*)d_in[8];
    const float* b2     = (const float*)d_in[9];
    const float* W3     = (const float*)d_in[10];
    const float* a_src3 = (const float*)d_in[11];
    const float* a_dst3 = (const float*)d_in[12];
    const float* b3     = (const float*)d_in[13];
    const float* Wl     = (const float*)d_in[14];
    const float* bl     = (const float*)d_in[15];
    const float* Wc     = (const float*)d_in[16];
    const float* bc     = (const float*)d_in[17];
    float* out = (float*)d_out;

    const int* src = ei;
    const int* dst = ei + EE;

    // workspace carve: two 41.4MB regions; hA/hB (fp16, 20.7MB each) use the lower halves,
    // weights + x16 live in regA's free upper half.
    char* p = (char*)d_ws;
    char* regA = p;  p += (size_t)MPAD*F1*4;
    char* regB = p;  p += (size_t)MPAD*F1*4;
    float* aw1  = (float*)p;  p += 16*IN_DIM*4;
    float* asrc = (float*)p;  p += (size_t)NN*HEADS*4;
    float* adst = (float*)p;  p += (size_t)NN*HEADS*4;
    int* cnt    = (int*)p;    p += NN*4;
    int* rowp   = (int*)p;    p += (NN+1)*4;
    int* cursor = (int*)p;    p += NN*4;
    int* colsrc = (int*)p;    p += EE*4;

    _Float16* hA = (_Float16*)regA;      // xa -> h2 -> h3 -> lin
    _Float16* hB = (_Float16*)regB;      // out1 -> out2 -> out3
    _Float16* up   = (_Float16*)(regA + (size_t)MPAD*F1*2);   // free upper half of regA
    _Float16* tW1  = up;                        // 1024*128
    _Float16* tW2  = tW1 + (size_t)F1*IN_DIM;   // 1024*1024
    _Float16* tW3  = tW2 + (size_t)F1*F1;       // 512*1024
    _Float16* tWl  = tW3 + (size_t)INT_DIM*F1;  // 512*512
    _Float16* x16  = tWl + (size_t)INT_DIM*INT_DIM;  // 10000*128

    // ---- fused prep (weights/x16/aw1/cnt-zero) + CSR build + alpha1 ----
    prep_kernel<<<3188, 256, 0, stream>>>(W1, W2, W3, Wl, x, a_src1, a_dst1,
                                          tW1, tW2, tW3, tWl, x16, aw1, cnt);
    count_alpha1_kernel<<<1250, 256, 0, stream>>>(dst, cnt, x, aw1, asrc, adst);
    scan_kernel<<<1, 1024, 0, stream>>>(cnt, rowp, cursor, NN);
    fill_kernel<<<(EE+255)/256, 256, 0, stream>>>(src, dst, EE, cursor, colsrc);

    // ---- Layer 1 (agg-first via linearity) ----
    agg1_kernel<<<NN/4, 256, 0, stream>>>(x16, asrc, adst, rowp, colsrc, hA);
    mfma16_gemm_kernel<1><<<dim3(MPAD/128, 1, HEADS), 512, 0, stream>>>(
        hA, F1, 128,  tW1, IN_DIM, 128*IN_DIM,
        b1, hB, F1, 128,  IN_DIM, 1);

    // ---- Layer 2 (project-first, fp16) ----
    mfma16_gemm_kernel<0><<<dim3((F1/128)*(MPAD/128), 1, 1), 512, 0, stream>>>(
        hB, F1, 0,  tW2, F1, 0,
        nullptr, hA, F1, 0,  F1, F1/128);
    alpha16_h8_kernel<<<NN, 128, 0, stream>>>(hA, a_src2, a_dst2, asrc, adst);
    agg2_kernel<<<(NN/4)*8, 256, 0, stream>>>(hA, asrc, adst, rowp, colsrc, b2, hB);

    // ---- Layer 3 (project-first, H=1, fp16) ----
    mfma16_gemm_kernel<0><<<dim3((INT_DIM/128)*(MPAD/128), 1, 1), 512, 0, stream>>>(
        hB, F1, 0,  tW3, F1, 0,
        nullptr, hA, INT_DIM, 0,  F1, INT_DIM/128);
    alpha16_h1_kernel<<<NN, 128, 0, stream>>>(hA, a_src3, a_dst3, asrc, adst);
    agg3_kernel<<<(NN/8)*8, 256, 0, stream>>>(hA, asrc, adst, rowp, colsrc, b3, hB);

    // ---- Linear: relu(out3 @ Wl + bl) -> hA fp16 [NN,512] ----
    mfma16_gemm_kernel<1><<<dim3((INT_DIM/128)*(MPAD/128), 1, 1), 512, 0, stream>>>(
        hB, INT_DIM, 0,  tWl, INT_DIM, 0,
        bl, hA, INT_DIM, 0,  INT_DIM, INT_DIM/128);

    // ---- Classifier ----
    cls16_kernel<<<(NN+3)/4, 256, 0, stream>>>(hA, Wc, bc, out, NN);
}